// Round 4
// baseline (434.337 us; speedup 1.0000x reference)
//
#include <hip/hip_runtime.h>
#include <hip/hip_bf16.h>

// Collapsed algebra:
//   out[i] = s * (A^12 x)[i] + t * (A^11 1)[i] + b11
// where A = D^{-1/2} (W + I) D^{-1/2} (self loops weight 1),
//   v = O_0 (O_1 (... (O_9 W11))),  O_k = Taylor_10(expm(Wk - Wk^T))
//   s = W0 . v,  t = b0 . v
//
// R1: 12x edge-scatter atomics -> CSR build + gathers.
// R2: ticket trick + u-space norm (raw weights in gather).
// R3: kill the 1.2M returning-atomic build. Bin edges by 256-node tiles
//     (LDS histogram + ~115k coarse atomics + LDS-staged coalesced writes),
//     then edge-parallel gathers accumulating into a per-bin LDS tile.

#define TPB 256
#define MAXBIN 1024          // supports N up to 262144 at 256 nodes/bin
#define PLACE_E 8192         // edges per place/hist block

// ---------------- v-chain: 100 sequential 64x64 matvecs, one block ----------
__device__ void v_chain(const float* __restrict__ W_orth,
                        const float* __restrict__ W11,
                        const float* __restrict__ W0,
                        const float* __restrict__ b0,
                        float* __restrict__ scal) {
    __shared__ float S[64 * 65];
    __shared__ float uvec[64];
    __shared__ float term[64];
    __shared__ float accv[64];
    const int tid = threadIdx.x;   // 256 threads

    if (tid < 64) uvec[tid] = W11[tid];
    __syncthreads();

    for (int k = 9; k >= 0; --k) {
        const float* Wk = W_orth + k * 4096;
        for (int e = tid; e < 4096; e += 256) {
            int i = e >> 6, j = e & 63;
            S[i * 65 + j] = Wk[i * 64 + j] - Wk[j * 64 + i];
        }
        __syncthreads();
        if (tid < 64) { term[tid] = uvec[tid]; accv[tid] = uvec[tid]; }
        __syncthreads();
        for (int t = 1; t <= 10; ++t) {
            const int r = tid >> 2, q = tid & 3;
            const int jb = q * 16;
            float p = 0.f;
            #pragma unroll
            for (int jj = 0; jj < 16; ++jj)
                p += S[r * 65 + jb + jj] * term[jb + jj];
            p += __shfl_xor(p, 1);
            p += __shfl_xor(p, 2);
            __syncthreads();
            if (q == 0) {
                float nt = p / (float)t;
                term[r] = nt;
                accv[r] += nt;
            }
            __syncthreads();
        }
        if (tid < 64) uvec[tid] = accv[tid];
        __syncthreads();
    }
    if (tid < 64) {
        float a = W0[tid] * uvec[tid];
        float b = b0[tid] * uvec[tid];
        #pragma unroll
        for (int off = 32; off; off >>= 1) {
            a += __shfl_down(a, off);
            b += __shfl_down(b, off);
        }
        if (tid == 0) { scal[0] = a; scal[1] = b; }
    }
}

// ---------------- kernels ---------------------------------------------------
__global__ void k_zero(int* __restrict__ binCnt) {
    binCnt[threadIdx.x] = 0;           // 1 block, MAXBIN threads
}

// per-block LDS histogram of targets by bin (c>>8), coarse flush to global.
// last block: Taylor v-chain.
__global__ void k_hist(const int* __restrict__ ei, int E,
                       int* __restrict__ binCnt, int nbin,
                       const float* __restrict__ W_orth,
                       const float* __restrict__ W11,
                       const float* __restrict__ W0,
                       const float* __restrict__ b0,
                       float* __restrict__ scal, int edge_blocks) {
    if ((int)blockIdx.x == edge_blocks) {
        v_chain(W_orth, W11, W0, b0, scal);
        return;
    }
    __shared__ int hist[MAXBIN];
    const int t = threadIdx.x;
    for (int b = t; b < MAXBIN; b += TPB) hist[b] = 0;
    __syncthreads();
    const int base = blockIdx.x * PLACE_E;
    for (int r = 0; r < PLACE_E / TPB; ++r) {
        int e = base + r * TPB + t;
        if (e < E) atomicAdd(&hist[ei[E + e] >> 8], 1);
    }
    __syncthreads();
    for (int b = t; b < nbin; b += TPB)
        if (hist[b]) atomicAdd(&binCnt[b], hist[b]);
}

// one block: exclusive scan binCnt -> binOff, zero binPos
__global__ void k_scan(const int* __restrict__ binCnt, int* __restrict__ binOff,
                       int* __restrict__ binPos, int nbin, int E) {
    __shared__ int s[MAXBIN];
    int t = threadIdx.x;               // 1024 threads
    int v = (t < nbin) ? binCnt[t] : 0;
    s[t] = v;
    __syncthreads();
    for (int o = 1; o < MAXBIN; o <<= 1) {
        int u = (t >= o) ? s[t - o] : 0;
        __syncthreads();
        s[t] += u;
        __syncthreads();
    }
    if (t < nbin) binOff[t] = s[t] - v;   // exclusive
    if (t == nbin - 1) binOff[nbin] = s[t];
    binPos[t] = 0;
}

// place edges into bin-grouped record array, coalesced via LDS staging.
// record: (src | clow<<18, weight_bits)
__global__ void k_place(const int* __restrict__ ei, const float* __restrict__ w,
                        int E, const int* __restrict__ binOff,
                        int* __restrict__ binPos, int2* __restrict__ rec,
                        int nbin) {
    __shared__ int hist[MAXBIN];          // pass A: counts; pass C: rank ctr
    __shared__ int starts[MAXBIN + 1];
    __shared__ int gbase[MAXBIN];
    __shared__ int psum[TPB];
    __shared__ int2 staged[PLACE_E];
    const int t = threadIdx.x;
    const int base = blockIdx.x * PLACE_E;
    const int nE = min(PLACE_E, E - base);

    for (int b = t; b < MAXBIN; b += TPB) hist[b] = 0;
    __syncthreads();
    // A: block histogram
    for (int r = 0; r < PLACE_E / TPB; ++r) {
        int e = base + r * TPB + t;
        if (e < E) atomicAdd(&hist[ei[E + e] >> 8], 1);
    }
    __syncthreads();
    // B: exclusive scan hist -> starts (4 elems per thread)
    {
        int b4 = t * 4;
        int h0 = hist[b4], h1 = hist[b4 + 1], h2 = hist[b4 + 2], h3 = hist[b4 + 3];
        int s1 = h0 + h1, s2 = s1 + h2, tot = s2 + h3;
        psum[t] = tot;
        __syncthreads();
        for (int o = 1; o < TPB; o <<= 1) {
            int u = (t >= o) ? psum[t - o] : 0;
            __syncthreads();
            psum[t] += u;
            __syncthreads();
        }
        int eb = psum[t] - tot;
        starts[b4]     = eb;
        starts[b4 + 1] = eb + h0;
        starts[b4 + 2] = eb + s1;
        starts[b4 + 3] = eb + s2;
        if (t == TPB - 1) starts[MAXBIN] = psum[t];
    }
    __syncthreads();
    // reserve global space per touched bin
    for (int b = t; b < nbin; b += TPB)
        if (hist[b]) gbase[b] = binOff[b] + atomicAdd(&binPos[b], hist[b]);
    __syncthreads();
    for (int b = t; b < MAXBIN; b += TPB) hist[b] = 0;   // reuse as rank ctr
    __syncthreads();
    // C: rank + stage
    for (int r = 0; r < PLACE_E / TPB; ++r) {
        int e = base + r * TPB + t;
        if (e < E) {
            int src = ei[e], c = ei[E + e];
            int bin = c >> 8;
            int rank = atomicAdd(&hist[bin], 1);
            staged[starts[bin] + rank] =
                make_int2(src | ((c & 255) << 18), __float_as_int(w[e]));
        }
    }
    __syncthreads();
    // D: coalesced write-out; recover bin by binary search in starts
    for (int s = t; s < nE; s += TPB) {
        int lo = 0, hi = MAXBIN;
        while (hi - lo > 1) {
            int mid = (lo + hi) >> 1;
            if (starts[mid] <= s) lo = mid; else hi = mid;
        }
        rec[gbase[lo] + (s - starts[lo])] = staged[s];
    }
}

// per-bin: deg = 1 + sum w; write dis, d2, u0 = dis*[x,1]
__global__ void k_deg(const int* __restrict__ binOff, const int2* __restrict__ rec,
                      const float* __restrict__ x, float* __restrict__ dis,
                      float* __restrict__ d2, float2* __restrict__ u, int N) {
    __shared__ float dacc[TPB];
    const int t = threadIdx.x, b = blockIdx.x;
    dacc[t] = 0.f;
    __syncthreads();
    for (int k = binOff[b] + t; k < binOff[b + 1]; k += TPB) {
        int2 rc = rec[k];
        atomicAdd(&dacc[rc.x >> 18], __int_as_float(rc.y));
    }
    __syncthreads();
    int i = b * 256 + t;
    if (i < N) {
        float deg = 1.0f + dacc[t];
        float ds = rsqrtf(deg);
        dis[i] = ds;
        d2[i] = 1.0f / deg;
        u[i] = make_float2(ds * x[i], ds);
    }
}

// one propagation in u-space, edge-parallel per bin with LDS accumulation
__global__ void k_gather(const int* __restrict__ binOff, const int2* __restrict__ rec,
                         const float* __restrict__ d2,
                         const float2* __restrict__ u, float2* __restrict__ out,
                         int N) {
    __shared__ float accx[TPB];
    __shared__ float accy[TPB];
    const int t = threadIdx.x, b = blockIdx.x;
    accx[t] = 0.f;
    accy[t] = 0.f;
    __syncthreads();
    for (int k = binOff[b] + t; k < binOff[b + 1]; k += TPB) {
        int2 rc = rec[k];
        float wv = __int_as_float(rc.y);
        float2 uv = u[rc.x & 0x3FFFF];
        int cl = rc.x >> 18;
        atomicAdd(&accx[cl], wv * uv.x);
        atomicAdd(&accy[cl], wv * uv.y);
    }
    __syncthreads();
    int i = b * 256 + t;
    if (i < N) {
        float2 ui = u[i];
        float sc = d2[i];
        out[i] = make_float2(sc * (ui.x + accx[t]), sc * (ui.y + accy[t]));
    }
}

__global__ void k_final(const float2* __restrict__ u12, const float2* __restrict__ u11,
                        const float* __restrict__ dis,
                        const float* __restrict__ scal, const float* __restrict__ b11,
                        float* __restrict__ out, int N) {
    int i = blockIdx.x * blockDim.x + threadIdx.x;
    if (i < N)
        out[i] = (scal[0] * u12[i].x + scal[1] * u11[i].y) / dis[i] + b11[0];
}

// ---------------- launch ----------------------------------------------------
extern "C" void kernel_launch(void* const* d_in, const int* in_sizes, int n_in,
                              void* d_out, int out_size, void* d_ws, size_t ws_size,
                              hipStream_t stream) {
    const float* x      = (const float*)d_in[0];
    const int*   ei     = (const int*)d_in[1];
    const float* w      = (const float*)d_in[2];
    const float* W0     = (const float*)d_in[3];
    const float* b0     = (const float*)d_in[4];
    const float* W_orth = (const float*)d_in[5];
    const float* W11    = (const float*)d_in[6];
    const float* b11    = (const float*)d_in[7];

    const int N = in_sizes[0];          // 200000
    const int E = in_sizes[2];          // 1200000
    const int nbin = (N + 255) / 256;   // 782

    // workspace layout
    char* ws = (char*)d_ws;
    float2* uA     = (float2*)ws;   ws += (size_t)N * 8;
    float2* uB     = (float2*)ws;   ws += (size_t)N * 8;
    int2*   rec    = (int2*)ws;     ws += (size_t)E * 8;
    float*  dis    = (float*)ws;    ws += (size_t)N * 4;
    float*  d2     = (float*)ws;    ws += (size_t)N * 4;
    int*    binCnt = (int*)ws;      ws += MAXBIN * 4;
    int*    binPos = (int*)ws;      ws += MAXBIN * 4;
    int*    binOff = (int*)ws;      ws += (MAXBIN + 1) * 4;
    float*  scal   = (float*)ws;    ws += 16;

    const int NB = (N + TPB - 1) / TPB;
    const int EB3 = (E + PLACE_E - 1) / PLACE_E;   // 147

    k_zero<<<1, MAXBIN, 0, stream>>>(binCnt);
    k_hist<<<EB3 + 1, TPB, 0, stream>>>(ei, E, binCnt, nbin,
                                        W_orth, W11, W0, b0, scal, EB3);
    k_scan<<<1, MAXBIN, 0, stream>>>(binCnt, binOff, binPos, nbin, E);
    k_place<<<EB3, TPB, 0, stream>>>(ei, w, E, binOff, binPos, rec, nbin);
    k_deg<<<nbin, TPB, 0, stream>>>(binOff, rec, x, dis, d2, uA, N);

    float2* prev = uA;
    float2* cur  = uB;
    for (int it = 0; it < 12; ++it) {
        k_gather<<<nbin, TPB, 0, stream>>>(binOff, rec, d2, prev, cur, N);
        float2* tmp = prev; prev = cur; cur = tmp;
    }
    // after swaps: prev = u12, cur = u11
    k_final<<<NB, TPB, 0, stream>>>(prev, cur, dis, scal, b11, (float*)d_out, N);
}